// Round 1
// baseline (1109.229 us; speedup 1.0000x reference)
//
#include <hip/hip_runtime.h>
#include <cmath>
#include <cstddef>

#define BB 8
#define LL 2048
#define EE 512
#define DD 64
#define HH 64
#define WW2 64
#define NBL (BB*LL)          // 16384
#define HW (HH*WW2)          // 4096

// Swizzled LDS tile index: 64x64 f32 tile, row stride 68 (16B-aligned rows),
// float4-granular XOR swizzle so both staging writes (consecutive col) and
// compute reads (16 distinct row-quads at fixed col-quad) stay <=2-way.
#define TIDX(r,c) (((r)*68) + (((((c)>>2) ^ (((r)>>2)&15)))<<2) + ((c)&3))

// ---------------- K0: one-time weight reorders ----------------
// w1r[(c*9+tap)*128 + o] = w1[o,c,ky,kx];  w2t[o*64 + d] = w2[d,o]
__global__ __launch_bounds__(256) void k_reorder(const float* __restrict__ w1,
        const float* __restrict__ w2,
        float* __restrict__ w1r, float* __restrict__ w2t) {
    int i = blockIdx.x * 256 + threadIdx.x;
    if (i < 73728) {
        int ct = i >> 7, o = i & 127;
        int c = ct / 9, tap = ct - c * 9;
        w1r[i] = w1[(size_t)(o * 64 + c) * 9 + tap];
    }
    if (i < 8192) {
        int o = i >> 6, d = i & 63;
        w2t[i] = w2[(size_t)d * 128 + o];
    }
}

// ---------------- K1: separable gaussians, normalized ----------------
// gyi[bl][h] = exp(-dy2/2si^2)/(Sy*Sx+1e-6); gxi[bl][w] = exp(-dx2/2si^2); same for out sigma
__global__ __launch_bounds__(256) void k_gauss(const float* __restrict__ pos,
        const float* __restrict__ lsig,
        float* __restrict__ gyi, float* __restrict__ gxi,
        float* __restrict__ gyo, float* __restrict__ gxo) {
    int lane = threadIdx.x & 63;
    int bl = blockIdx.x * 4 + (threadIdx.x >> 6);
    float ls = lsig[0];
    float si = log1pf(expf(ls)) + 1e-6f;      // softplus + eps
    float so = si * 2.0f;
    float ai = 1.0f / (2.0f * si * si);
    float ao = 1.0f / (2.0f * so * so);
    float py = pos[(size_t)bl * 2 + 0];
    float px = pos[(size_t)bl * 2 + 1];
    float dy = (float)lane - py, dx = (float)lane - px;
    float dy2 = dy * dy, dx2 = dx * dx;
    float gy_i = expf(-dy2 * ai), gx_i = expf(-dx2 * ai);
    float gy_o = expf(-dy2 * ao), gx_o = expf(-dx2 * ao);
    float syi = gy_i, sxi = gx_i, syo = gy_o, sxo = gx_o;
    #pragma unroll
    for (int off = 32; off > 0; off >>= 1) {
        syi += __shfl_xor(syi, off);
        sxi += __shfl_xor(sxi, off);
        syo += __shfl_xor(syo, off);
        sxo += __shfl_xor(sxo, off);
    }
    float zi = syi * sxi + 1e-6f;
    float zo = syo * sxo + 1e-6f;
    size_t base = (size_t)bl * 64 + lane;
    gyi[base] = gy_i / zi;
    gxi[base] = gx_i;
    gyo[base] = gy_o / zo;
    gxo[base] = gx_o;
}

// ---------------- K2: proj = tokens @ W_to_field^T ----------------
// proj[n,d] = sum_e tokens[n,e]*wtf[d,e];  64n x 64d tile per block, K=512
__global__ __launch_bounds__(256) void k_proj(const float* __restrict__ tokens,
        const float* __restrict__ wtf, float* __restrict__ proj) {
    __shared__ float At[68 * 64], Bt[68 * 64];
    int t = threadIdx.x;
    int n0 = blockIdx.x * 64;
    int nq = t >> 4, dq = t & 15;
    float acc[4][4] = {};
    for (int e0 = 0; e0 < EE; e0 += 64) {
        __syncthreads();
        for (int i = t; i < 1024; i += 256) {
            int row = i >> 4, c4 = (i & 15) << 2;
            *(float4*)&At[TIDX(row, c4)] =
                *(const float4*)&tokens[(size_t)(n0 + row) * EE + e0 + c4];
            *(float4*)&Bt[TIDX(row, c4)] =
                *(const float4*)&wtf[(size_t)row * EE + e0 + c4];
        }
        __syncthreads();
        #pragma unroll
        for (int eq = 0; eq < 16; eq++) {
            float4 a[4], b[4];
            #pragma unroll
            for (int i = 0; i < 4; i++) a[i] = *(float4*)&At[TIDX(nq * 4 + i, eq * 4)];
            #pragma unroll
            for (int j = 0; j < 4; j++) b[j] = *(float4*)&Bt[TIDX(dq * 4 + j, eq * 4)];
            #pragma unroll
            for (int i = 0; i < 4; i++) {
                #pragma unroll
                for (int j = 0; j < 4; j++) {
                    acc[i][j] += a[i].x * b[j].x + a[i].y * b[j].y
                               + a[i].z * b[j].z + a[i].w * b[j].w;
                }
            }
        }
    }
    #pragma unroll
    for (int i = 0; i < 4; i++) {
        float4 v = {acc[i][0], acc[i][1], acc[i][2], acc[i][3]};
        *(float4*)&proj[(size_t)(n0 + nq * 4 + i) * DD + dq * 4] = v;
    }
}

// ---------------- K3: field[b,c,h,:] = sum_l proj[b,l,c] * gyi[b,l,h]*gxi[b,l,:] ----
// block = (h, b); 64c x 64w outputs; reduction over l in chunks of 64 (outer product)
__global__ __launch_bounds__(256) void k_scatter(const float* __restrict__ proj,
        const float* __restrict__ gyi, const float* __restrict__ gxi,
        float* __restrict__ field) {
    __shared__ float Pt[68 * 64], Qt[68 * 64];
    int t = threadIdx.x;
    int h = blockIdx.x;
    int b = blockIdx.y;
    int cq = t >> 4, wq = t & 15;
    float acc[4][4] = {};
    for (int l0 = 0; l0 < LL; l0 += 64) {
        __syncthreads();
        for (int i = t; i < 1024; i += 256) {
            int row = i >> 4, c4 = (i & 15) << 2;
            size_t bl = (size_t)b * LL + l0 + row;
            *(float4*)&Pt[TIDX(row, c4)] = *(const float4*)&proj[bl * DD + c4];
            float gy = gyi[bl * 64 + h];
            float4 gx = *(const float4*)&gxi[bl * 64 + c4];
            float4 q = {gy * gx.x, gy * gx.y, gy * gx.z, gy * gx.w};
            *(float4*)&Qt[TIDX(row, c4)] = q;
        }
        __syncthreads();
        #pragma unroll 8
        for (int l = 0; l < 64; l++) {
            float4 a = *(float4*)&Pt[TIDX(l, cq * 4)];
            float4 q = *(float4*)&Qt[TIDX(l, wq * 4)];
            float av[4] = {a.x, a.y, a.z, a.w};
            float bv[4] = {q.x, q.y, q.z, q.w};
            #pragma unroll
            for (int i = 0; i < 4; i++) {
                #pragma unroll
                for (int j = 0; j < 4; j++) acc[i][j] += av[i] * bv[j];
            }
        }
    }
    #pragma unroll
    for (int i = 0; i < 4; i++) {
        float4 v = {acc[i][0], acc[i][1], acc[i][2], acc[i][3]};
        *(float4*)&field[(((size_t)b * DD + cq * 4 + i) * HH + h) * WW2 + wq * 4] = v;
    }
}

// ---------------- K4: fused conv step ----------------
// fout = fin + conv2(relu(conv1(fin)));  8x8 spatial tile per block, batch=blockIdx.y
__global__ __launch_bounds__(256) void k_conv(const float* __restrict__ fin,
        float* __restrict__ fout,
        const float* __restrict__ w1r, const float* __restrict__ b1,
        const float* __restrict__ w2t, const float* __restrict__ b2) {
    __shared__ float in_t[64][10][12];          // 30720 B
    __shared__ float wbuf[8192 + 32 * 68];      // w1 chunk (9216 f) / h(8192 f)+w2s(2176 f)
    int t = threadIdx.x;
    int b = blockIdx.y;
    int tile = blockIdx.x;
    int y0 = (tile >> 3) << 3, x0 = (tile & 7) << 3;
    const float* fb = fin + (size_t)b * DD * HW;

    // stage input tile with halo (zero pad)
    for (int i = t; i < 6400; i += 256) {
        int c = i / 100;
        int r = i - c * 100;
        int iy = r / 10, ix = r - iy * 10;
        int gy = y0 + iy - 1, gx = x0 + ix - 1;
        float v = 0.f;
        if ((unsigned)gy < 64u && (unsigned)gx < 64u)
            v = fb[(size_t)c * HW + gy * 64 + gx];
        in_t[c][iy][ix] = v;
    }

    int px = t & 63;
    int pyy = px >> 3, pxx = px & 7;
    int g = t >> 6;
    int o0 = g * 32;
    float acc[32];
    #pragma unroll
    for (int i = 0; i < 32; i++) acc[i] = b1[o0 + i];
    __syncthreads();

    // conv1: each thread = 1 pixel x 32 out-channels
    for (int cc = 0; cc < 64; cc += 8) {
        for (int i = t; i < 9216; i += 256) wbuf[i] = w1r[(size_t)cc * 9 * 128 + i];
        __syncthreads();
        #pragma unroll
        for (int c = 0; c < 8; c++) {
            #pragma unroll
            for (int ky = 0; ky < 3; ky++) {
                #pragma unroll
                for (int kx = 0; kx < 3; kx++) {
                    float v = in_t[cc + c][pyy + ky][pxx + kx];
                    const float* wr = &wbuf[(c * 9 + ky * 3 + kx) * 128 + o0];
                    #pragma unroll
                    for (int k = 0; k < 32; k += 4) {
                        float4 w4 = *(const float4*)(wr + k);
                        acc[k]     += v * w4.x;
                        acc[k + 1] += v * w4.y;
                        acc[k + 2] += v * w4.z;
                        acc[k + 3] += v * w4.w;
                    }
                }
            }
        }
        __syncthreads();
    }

    // relu -> h in LDS [128][64]
    float* hbuf = wbuf;
    #pragma unroll
    for (int i = 0; i < 32; i++) hbuf[(o0 + i) * 64 + px] = fmaxf(acc[i], 0.f);

    // conv2 (1x1, 128->64) + bias; thread = 4d x 4px outer product
    int dq = t & 15, pq = t >> 4;
    int d0 = dq * 4, p0 = pq * 4;
    float acc2[4][4];
    #pragma unroll
    for (int i = 0; i < 4; i++) {
        float bv = b2[d0 + i];
        #pragma unroll
        for (int j = 0; j < 4; j++) acc2[i][j] = bv;
    }
    float* w2s = wbuf + 8192;  // [32][68]
    for (int oc = 0; oc < 128; oc += 32) {
        for (int i = t; i < 2048; i += 256) {
            int o = i >> 6, d = i & 63;
            w2s[o * 68 + d] = w2t[(size_t)(oc + o) * 64 + d];
        }
        __syncthreads();
        #pragma unroll 4
        for (int o = 0; o < 32; o++) {
            float4 wv = *(const float4*)&w2s[o * 68 + d0];
            float4 hv = *(const float4*)&hbuf[(oc + o) * 64 + p0];
            float w[4] = {wv.x, wv.y, wv.z, wv.w};
            float hh[4] = {hv.x, hv.y, hv.z, hv.w};
            #pragma unroll
            for (int i = 0; i < 4; i++) {
                #pragma unroll
                for (int j = 0; j < 4; j++) acc2[i][j] += w[i] * hh[j];
            }
        }
        __syncthreads();
    }

    // residual + store
    #pragma unroll
    for (int i = 0; i < 4; i++) {
        #pragma unroll
        for (int j = 0; j < 4; j++) {
            int p = p0 + j;
            acc2[i][j] += in_t[d0 + i][1 + (p >> 3)][1 + (p & 7)];
        }
        int yy = p0 >> 3, xx = p0 & 7;
        float4 v = {acc2[i][0], acc2[i][1], acc2[i][2], acc2[i][3]};
        *(float4*)&fout[(((size_t)b * DD + d0 + i) * HH + y0 + yy) * WW2 + x0 + xx] = v;
    }
}

// ---------------- K5: sampled[b,l,c] = sum_hw wout[l,hw]*field[c,hw] ----------------
// block = (ltile, b); 64l x 64c outputs; K over hw, staged one h-row (64 w) at a time
__global__ __launch_bounds__(256) void k_gather(const float* __restrict__ field,
        const float* __restrict__ gyo, const float* __restrict__ gxo,
        float* __restrict__ sampled) {
    __shared__ float Wt[68 * 64], Ft[68 * 64];
    int t = threadIdx.x;
    int b = blockIdx.y;
    int l0 = blockIdx.x * 64;
    int lq = t >> 4, cq = t & 15;
    float acc[4][4] = {};
    const float* fb = field + (size_t)b * DD * HW;
    for (int h = 0; h < 64; h++) {
        __syncthreads();
        for (int i = t; i < 1024; i += 256) {
            int row = i >> 4, c4 = (i & 15) << 2;
            *(float4*)&Ft[TIDX(row, c4)] =
                *(const float4*)&fb[(size_t)row * HW + h * 64 + c4];
            size_t bl = (size_t)b * LL + l0 + row;
            float gy = gyo[bl * 64 + h];
            float4 gx = *(const float4*)&gxo[bl * 64 + c4];
            float4 q = {gy * gx.x, gy * gx.y, gy * gx.z, gy * gx.w};
            *(float4*)&Wt[TIDX(row, c4)] = q;
        }
        __syncthreads();
        #pragma unroll
        for (int wq = 0; wq < 16; wq++) {
            float4 a[4], f[4];
            #pragma unroll
            for (int i = 0; i < 4; i++) a[i] = *(float4*)&Wt[TIDX(lq * 4 + i, wq * 4)];
            #pragma unroll
            for (int j = 0; j < 4; j++) f[j] = *(float4*)&Ft[TIDX(cq * 4 + j, wq * 4)];
            #pragma unroll
            for (int i = 0; i < 4; i++) {
                #pragma unroll
                for (int j = 0; j < 4; j++) {
                    acc[i][j] += a[i].x * f[j].x + a[i].y * f[j].y
                               + a[i].z * f[j].z + a[i].w * f[j].w;
                }
            }
        }
    }
    #pragma unroll
    for (int i = 0; i < 4; i++) {
        float4 v = {acc[i][0], acc[i][1], acc[i][2], acc[i][3]};
        *(float4*)&sampled[((size_t)b * LL + l0 + lq * 4 + i) * DD + cq * 4] = v;
    }
}

// ---------------- K6: tokens_out = sampled @ W_from_field^T ----------------
// out[n,e] = sum_d sampled[n,d]*wff[e,d]; 64n x 64e per block, K=64
__global__ __launch_bounds__(256) void k_out(const float* __restrict__ sampled,
        const float* __restrict__ wff, float* __restrict__ out) {
    __shared__ float At[68 * 64], Bt[68 * 64];
    int t = threadIdx.x;
    int n0 = blockIdx.x * 64;
    int e0 = blockIdx.y * 64;
    int nq = t >> 4, eq = t & 15;
    for (int i = t; i < 1024; i += 256) {
        int row = i >> 4, c4 = (i & 15) << 2;
        *(float4*)&At[TIDX(row, c4)] = *(const float4*)&sampled[(size_t)(n0 + row) * DD + c4];
        *(float4*)&Bt[TIDX(row, c4)] = *(const float4*)&wff[(size_t)(e0 + row) * DD + c4];
    }
    __syncthreads();
    float acc[4][4] = {};
    #pragma unroll
    for (int dq = 0; dq < 16; dq++) {
        float4 a[4], b[4];
        #pragma unroll
        for (int i = 0; i < 4; i++) a[i] = *(float4*)&At[TIDX(nq * 4 + i, dq * 4)];
        #pragma unroll
        for (int j = 0; j < 4; j++) b[j] = *(float4*)&Bt[TIDX(eq * 4 + j, dq * 4)];
        #pragma unroll
        for (int i = 0; i < 4; i++) {
            #pragma unroll
            for (int j = 0; j < 4; j++) {
                acc[i][j] += a[i].x * b[j].x + a[i].y * b[j].y
                           + a[i].z * b[j].z + a[i].w * b[j].w;
            }
        }
    }
    #pragma unroll
    for (int i = 0; i < 4; i++) {
        float4 v = {acc[i][0], acc[i][1], acc[i][2], acc[i][3]};
        *(float4*)&out[(size_t)(n0 + nq * 4 + i) * EE + e0 + eq * 4] = v;
    }
}

extern "C" void kernel_launch(void* const* d_in, const int* in_sizes, int n_in,
                              void* d_out, int out_size, void* d_ws, size_t ws_size,
                              hipStream_t stream) {
    const float* tokens = (const float*)d_in[0];
    const float* pos    = (const float*)d_in[1];
    const float* wtf    = (const float*)d_in[2];
    const float* wff    = (const float*)d_in[3];
    const float* w1     = (const float*)d_in[4];
    const float* b1     = (const float*)d_in[5];
    const float* w2     = (const float*)d_in[6];
    const float* b2     = (const float*)d_in[7];
    const float* lsig   = (const float*)d_in[8];
    float* out = (float*)d_out;

    float* ws  = (float*)d_ws;
    float* gyi = ws;                         // NBL*64
    float* gxi = gyi + (size_t)NBL * 64;
    float* gyo = gxi + (size_t)NBL * 64;
    float* gxo = gyo + (size_t)NBL * 64;
    float* proj = gxo + (size_t)NBL * 64;    // NBL*64
    float* fA  = proj + (size_t)NBL * 64;    // B*D*HW
    float* fB  = fA + (size_t)BB * DD * HW;
    float* samp = fB + (size_t)BB * DD * HW; // NBL*64
    float* w1r = samp + (size_t)NBL * 64;    // 73728
    float* w2t = w1r + 73728;                // 8192

    hipLaunchKernelGGL(k_reorder, dim3(288), dim3(256), 0, stream, w1, w2, w1r, w2t);
    hipLaunchKernelGGL(k_gauss, dim3(NBL / 4), dim3(256), 0, stream,
                       pos, lsig, gyi, gxi, gyo, gxo);
    hipLaunchKernelGGL(k_proj, dim3(256), dim3(256), 0, stream, tokens, wtf, proj);
    hipLaunchKernelGGL(k_scatter, dim3(64, 8), dim3(256), 0, stream, proj, gyi, gxi, fA);

    const float* ci = fA;
    float* co = fB;
    for (int s = 0; s < 5; s++) {
        hipLaunchKernelGGL(k_conv, dim3(64, 8), dim3(256), 0, stream,
                           ci, co, w1r, b1, w2t, b2);
        float* tmp = co; co = (float*)ci; ci = tmp;
    }
    // after 5 steps final field is in `ci`
    hipLaunchKernelGGL(k_gather, dim3(32, 8), dim3(256), 0, stream, ci, gyo, gxo, samp);
    hipLaunchKernelGGL(k_out, dim3(256, 8), dim3(256), 0, stream, samp, wff, out);
}

// Round 3
// 260.334 us; speedup vs baseline: 4.2608x; 4.2608x over previous
//
#include <hip/hip_runtime.h>
#include <cmath>
#include <cstddef>

#define BB 8
#define LL 2048
#define EE 512
#define DD 64
#define HH 64
#define HW 4096

typedef __attribute__((ext_vector_type(8))) short short8;
typedef __attribute__((ext_vector_type(4))) short short4v;
typedef __attribute__((ext_vector_type(4))) float f32x4;

// XOR-swizzled LDS index (bf16 elements). ldk = row length in bf16 elems.
// 16B-granule g XORed with low row bits -> conflict-free ds_read_b128 per T2.
__device__ __forceinline__ int swz(int row, int k, int ldk) {
    int g = (k >> 3) ^ (row & ((ldk >> 3) - 1));
    return row * ldk + (g << 3) + (k & 7);
}

__device__ __forceinline__ unsigned short f2bf(float f) {   // RNE f32->bf16
    unsigned u = __builtin_bit_cast(unsigned, f);
    return (unsigned short)((u + 0x7FFFu + ((u >> 16) & 1u)) >> 16);
}
__device__ __forceinline__ short4v cvt4(float4 v) {
    short4v r;
    r[0] = (short)f2bf(v.x); r[1] = (short)f2bf(v.y);
    r[2] = (short)f2bf(v.z); r[3] = (short)f2bf(v.w);
    return r;
}
#define MFMA16(acc, a, b) acc = __builtin_amdgcn_mfma_f32_16x16x32_bf16(a, b, acc, 0, 0, 0)

// ---------------- K0: weight reorders -> bf16 ----------------
// w1b[(tap*128+o)*64+c] = w1[o,c,ky,kx]  (tap=ky*3+kx);  w2b[d*128+o] = w2[d,o]
__global__ __launch_bounds__(256) void k_reorder(const float* __restrict__ w1,
        const float* __restrict__ w2,
        short* __restrict__ w1b, short* __restrict__ w2b) {
    int i = blockIdx.x * 256 + threadIdx.x;
    if (i < 73728) {
        int c = i & 63, o = (i >> 6) & 127, tap = i >> 13;
        w1b[i] = (short)f2bf(w1[(size_t)o * 576 + c * 9 + tap]);
    }
    if (i < 8192) w2b[i] = (short)f2bf(w2[i]);
}

// ---------------- K1: separable gaussians (transposed tables) ----------------
// gyiT[b][h][l] (with /Zi), gxiT[b][w][l], gyoT[b][h][l] (with /Zo), gxo[b][l][w]
__global__ __launch_bounds__(256) void k_gauss(const float* __restrict__ pos,
        const float* __restrict__ lsig,
        float* __restrict__ gyiT, float* __restrict__ gxiT,
        float* __restrict__ gyoT, float* __restrict__ gxo) {
    __shared__ float red[4][4][64];
    __shared__ float tile[64 * 65];
    int t = threadIdx.x;
    int ll = t & 63, q = t >> 6;
    int b = blockIdx.y, lt = blockIdx.x;
    int bl = b * LL + lt * 64 + ll;
    float py = pos[(size_t)bl * 2 + 0];
    float px = pos[(size_t)bl * 2 + 1];
    float ls = lsig[0];
    float si = log1pf(expf(ls)) + 1e-6f;
    float so = si * 2.0f;
    float ai = 0.5f / (si * si), ao = 0.5f / (so * so);
    float vyi[16], vxi[16], vyo[16], vxo[16];
    float pyi = 0.f, pxi = 0.f, pyo = 0.f, pxo = 0.f;
    #pragma unroll
    for (int j = 0; j < 16; j++) {
        float g = (float)(q * 16 + j);
        float dy = g - py, dx = g - px;
        float dy2 = dy * dy, dx2 = dx * dx;
        vyi[j] = expf(-dy2 * ai); pyi += vyi[j];
        vxi[j] = expf(-dx2 * ai); pxi += vxi[j];
        vyo[j] = expf(-dy2 * ao); pyo += vyo[j];
        vxo[j] = expf(-dx2 * ao); pxo += vxo[j];
    }
    red[0][q][ll] = pyi; red[1][q][ll] = pxi;
    red[2][q][ll] = pyo; red[3][q][ll] = pxo;
    __syncthreads();
    float syi = red[0][0][ll] + red[0][1][ll] + red[0][2][ll] + red[0][3][ll];
    float sxi = red[1][0][ll] + red[1][1][ll] + red[1][2][ll] + red[1][3][ll];
    float syo = red[2][0][ll] + red[2][1][ll] + red[2][2][ll] + red[2][3][ll];
    float sxo = red[3][0][ll] + red[3][1][ll] + red[3][2][ll] + red[3][3][ll];
    float inv_i = 1.0f / (syi * sxi + 1e-6f);
    float inv_o = 1.0f / (syo * sxo + 1e-6f);
    size_t base = (size_t)b * 64 * LL + lt * 64 + ll;   // [b][*][l]
    #pragma unroll
    for (int j = 0; j < 16; j++) {
        size_t off = base + (size_t)(q * 16 + j) * LL;
        gyiT[off] = vyi[j] * inv_i;
        gxiT[off] = vxi[j];
        gyoT[off] = vyo[j] * inv_o;
        tile[(q * 16 + j) * 65 + ll] = vxo[j];
    }
    __syncthreads();
    #pragma unroll
    for (int j = 0; j < 16; j++) {
        int i = t + 256 * j;
        int lo = i >> 6, wo = i & 63;
        gxo[((size_t)b * LL + lt * 64 + lo) * 64 + wo] = tile[wo * 65 + lo];
    }
}

// ---------------- K2: projT[b][d][l] = sum_e wtf[d,e]*tokens[b,l,e] ----------------
__global__ __launch_bounds__(256) void k_proj(const float* __restrict__ tokens,
        const float* __restrict__ wtf, float* __restrict__ projT) {
    __shared__ __align__(16) short At[4096], Bt[4096];
    int t = threadIdx.x, lane = t & 63, wid = t >> 6;
    int blk = blockIdx.x;
    int b = blk >> 5;
    int l0b = (blk & 31) * 64;
    size_t tokbase = ((size_t)b * LL + l0b) * EE;
    f32x4 z = {0.f, 0.f, 0.f, 0.f};
    f32x4 acc[4] = {z, z, z, z};
    float4 pa[4], pb[4];
    #pragma unroll
    for (int j = 0; j < 4; j++) {
        int idx = t + 256 * j;
        int row = idx >> 4, kq = (idx & 15) << 2;
        pa[j] = *(const float4*)&wtf[(size_t)row * EE + kq];
        pb[j] = *(const float4*)&tokens[tokbase + (size_t)row * EE + kq];
    }
    for (int c = 0; c < 8; c++) {
        __syncthreads();
        #pragma unroll
        for (int j = 0; j < 4; j++) {
            int idx = t + 256 * j;
            int row = idx >> 4, kq = (idx & 15) << 2;
            *(short4v*)&At[swz(row, kq, 64)] = cvt4(pa[j]);
            *(short4v*)&Bt[swz(row, kq, 64)] = cvt4(pb[j]);
        }
        __syncthreads();
        if (c < 7) {
            int e0 = (c + 1) * 64;
            #pragma unroll
            for (int j = 0; j < 4; j++) {
                int idx = t + 256 * j;
                int row = idx >> 4, kq = (idx & 15) << 2;
                pa[j] = *(const float4*)&wtf[(size_t)row * EE + e0 + kq];
                pb[j] = *(const float4*)&tokens[tokbase + (size_t)row * EE + e0 + kq];
            }
        }
        int mrow = wid * 16 + (lane & 15);
        #pragma unroll
        for (int ks = 0; ks < 2; ks++) {
            int k0 = ks * 32 + (lane >> 4) * 8;
            short8 a = *(short8*)&At[swz(mrow, k0, 64)];
            #pragma unroll
            for (int n = 0; n < 4; n++) {
                short8 bb = *(short8*)&Bt[swz(n * 16 + (lane & 15), k0, 64)];
                MFMA16(acc[n], a, bb);
            }
        }
    }
    #pragma unroll
    for (int n = 0; n < 4; n++)
        #pragma unroll
        for (int r = 0; r < 4; r++) {
            int d = wid * 16 + ((lane >> 4) << 2) + r;
            int l = l0b + n * 16 + (lane & 15);
            projT[((size_t)b * 64 + d) * LL + l] = acc[n][r];
        }
}

// ---------------- K3: scatter -> fieldT (NHWC) ----------------
// fieldT[b][h][w][c] = sum_l projT[b][c][l]*gyiT[b][h][l]*gxiT[b][w][l]
__global__ __launch_bounds__(256) void k_scatter(const float* __restrict__ projT,
        const float* __restrict__ gyiT, const float* __restrict__ gxiT,
        float* __restrict__ fieldT) {
    __shared__ __align__(16) char smem[24576];
    short* At0 = (short*)smem;              // [64 c][64 l]
    short* At1 = At0 + 4096;
    short* Bt  = At1 + 4096;                // [64 w][64 l]
    float* Cf  = (float*)smem;              // 64*68 f32 overlay (epilogue)
    int t = threadIdx.x, lane = t & 63, wid = t >> 6;
    int hp = blockIdx.x, b = blockIdx.y;
    int h0 = hp * 2;
    f32x4 z = {0.f, 0.f, 0.f, 0.f};
    f32x4 acc0[4] = {z, z, z, z}, acc1[4] = {z, z, z, z};
    const float* gy0 = gyiT + ((size_t)b * 64 + h0) * LL;
    const float* gy1 = gyiT + ((size_t)b * 64 + h0 + 1) * LL;
    float4 pp[4], pg[4], py0[4], py1[4];
    #pragma unroll
    for (int j = 0; j < 4; j++) {
        int idx = t + 256 * j;
        int row = idx >> 4, kq = (idx & 15) << 2;
        pp[j]  = *(const float4*)&projT[((size_t)b * 64 + row) * LL + kq];
        pg[j]  = *(const float4*)&gxiT[((size_t)b * 64 + row) * LL + kq];
        py0[j] = *(const float4*)&gy0[kq];
        py1[j] = *(const float4*)&gy1[kq];
    }
    for (int c = 0; c < 32; c++) {
        __syncthreads();
        #pragma unroll
        for (int j = 0; j < 4; j++) {
            int idx = t + 256 * j;
            int row = idx >> 4, kq = (idx & 15) << 2;
            float4 a0 = {pp[j].x * py0[j].x, pp[j].y * py0[j].y,
                         pp[j].z * py0[j].z, pp[j].w * py0[j].w};
            float4 a1 = {pp[j].x * py1[j].x, pp[j].y * py1[j].y,
                         pp[j].z * py1[j].z, pp[j].w * py1[j].w};
            *(short4v*)&At0[swz(row, kq, 64)] = cvt4(a0);
            *(short4v*)&At1[swz(row, kq, 64)] = cvt4(a1);
            *(short4v*)&Bt[swz(row, kq, 64)]  = cvt4(pg[j]);
        }
        __syncthreads();
        if (c < 31) {
            int l0 = (c + 1) * 64;
            #pragma unroll
            for (int j = 0; j < 4; j++) {
                int idx = t + 256 * j;
                int row = idx >> 4, kq = (idx & 15) << 2;
                pp[j]  = *(const float4*)&projT[((size_t)b * 64 + row) * LL + l0 + kq];
                pg[j]  = *(const float4*)&gxiT[((size_t)b * 64 + row) * LL + l0 + kq];
                py0[j] = *(const float4*)&gy0[l0 + kq];
                py1[j] = *(const float4*)&gy1[l0 + kq];
            }
        }
        int mrow = wid * 16 + (lane & 15);
        #pragma unroll
        for (int ks = 0; ks < 2; ks++) {
            int k0 = ks * 32 + (lane >> 4) * 8;
            short8 a0 = *(short8*)&At0[swz(mrow, k0, 64)];
            short8 a1 = *(short8*)&At1[swz(mrow, k0, 64)];
            #pragma unroll
            for (int n = 0; n < 4; n++) {
                short8 bb = *(short8*)&Bt[swz(n * 16 + (lane & 15), k0, 64)];
                MFMA16(acc0[n], a0, bb);
                MFMA16(acc1[n], a1, bb);
            }
        }
    }
    // epilogue: transpose [c][w] -> [w][c] in LDS, coalesced NHWC store
    #pragma unroll
    for (int p = 0; p < 2; p++) {
        __syncthreads();
        #pragma unroll
        for (int n = 0; n < 4; n++)
            #pragma unroll
            for (int r = 0; r < 4; r++) {
                int w = n * 16 + (lane & 15);
                int cc = wid * 16 + ((lane >> 4) << 2) + r;
                Cf[w * 68 + cc] = (p == 0) ? acc0[n][r] : acc1[n][r];
            }
        __syncthreads();
        #pragma unroll
        for (int j = 0; j < 4; j++) {
            int i = t + 256 * j;
            int wo = i >> 4, cq = (i & 15) << 2;
            *(float4*)&fieldT[(((size_t)b * 64 + h0 + p) * 64 + wo) * 64 + cq] =
                *(float4*)&Cf[wo * 68 + cq];
        }
    }
}

// ---------------- K4: fused conv step (implicit GEMM, NHWC) ----------------
__global__ __launch_bounds__(256) void k_conv(const float* __restrict__ fin,
        float* __restrict__ fout,
        const short* __restrict__ w1b, const float* __restrict__ b1,
        const short* __restrict__ w2b, const float* __restrict__ b2,
        float* __restrict__ fnchw, int final_step) {
    __shared__ __align__(16) char smem[61952];
    short* halo = (short*)smem;             // [100 px][64 c] swz64  (12800 B)
    short* w1t  = (short*)(smem + 12800);   // [128 o][64 c] swz64  (16384 B)
    short* ht   = (short*)(smem + 29184);   // [64 px][128 o] swz128(16384 B)
    short* w2s  = (short*)(smem + 45568);   // [64 d][128 o] swz128 (16384 B)
    float* Cf   = (float*)smem;             // 64*68 f32 overlay (final epi)
    int t = threadIdx.x, lane = t & 63, wid = t >> 6;
    int tile = blockIdx.x, b = blockIdx.y;
    int y0 = (tile >> 3) << 3, x0 = (tile & 7) << 3;
    const float* fb = fin + (size_t)b * 64 * HW;   // NHWC base: [h][w][c]

    // stage halo (f32 -> bf16, zero-padded)
    for (int i = t; i < 1600; i += 256) {
        int pix = i >> 4, cq = (i & 15) << 2;
        int pr = pix / 10, pc = pix - pr * 10;
        int gy = y0 + pr - 1, gx = x0 + pc - 1;
        float4 v = {0.f, 0.f, 0.f, 0.f};
        if ((unsigned)gy < 64u && (unsigned)gx < 64u)
            v = *(const float4*)&fb[((size_t)gy * 64 + gx) * 64 + cq];
        *(short4v*)&halo[swz(pix, cq, 64)] = cvt4(v);
    }
    // stage w2 (bf16 global -> LDS swz128)
    for (int i = t; i < 1024; i += 256) {
        int d = i >> 4, g = i & 15;
        short8 v = *(const short8*)&w2b[(size_t)d * 128 + g * 8];
        *(short8*)&w2s[swz(d, g * 8, 128)] = v;
    }
    // conv1 acc init with bias (col = o)
    f32x4 accH[8];
    #pragma unroll
    for (int n = 0; n < 8; n++) {
        float bv = b1[n * 16 + (lane & 15)];
        f32x4 v = {bv, bv, bv, bv};
        accH[n] = v;
    }
    // prefetch w1 tap 0 (128 o x 64 c = 1024 short8 granules, 4 per thread)
    short8 w1pf[4];
    #pragma unroll
    for (int j = 0; j < 4; j++) {
        int i = t + 256 * j;
        int o = i >> 3, g = i & 7;
        w1pf[j] = *(const short8*)&w1b[((size_t)o) * 64 + g * 8];
    }
    int mpix = wid * 16 + (lane & 15);
    int ppy = mpix >> 3, ppx = mpix & 7;

    #pragma unroll
    for (int tap = 0; tap < 9; tap++) {
        int ky = tap / 3, kx = tap - ky * 3;
        __syncthreads();
        #pragma unroll
        for (int j = 0; j < 4; j++) {
            int i = t + 256 * j;
            int o = i >> 3, g = i & 7;
            *(short8*)&w1t[swz(o, g * 8, 64)] = w1pf[j];
        }
        __syncthreads();
        if (tap < 8) {
            #pragma unroll
            for (int j = 0; j < 4; j++) {
                int i = t + 256 * j;
                int o = i >> 3, g = i & 7;
                w1pf[j] = *(const short8*)&w1b[((size_t)(tap + 1) * 128 + o) * 64 + g * 8];
            }
        }
        int hpix = (ppy + ky) * 10 + (ppx + kx);
        #pragma unroll
        for (int ks = 0; ks < 2; ks++) {
            int k0 = ks * 32 + (lane >> 4) * 8;
            short8 a = *(short8*)&halo[swz(hpix, k0, 64)];
            #pragma unroll
            for (int n = 0; n < 8; n++) {
                short8 bb = *(short8*)&w1t[swz(n * 16 + (lane & 15), k0, 64)];
                MFMA16(accH[n], a, bb);
            }
        }
    }
    // relu -> Ht (bf16)
    #pragma unroll
    for (int n = 0; n < 8; n++)
        #pragma unroll
        for (int r = 0; r < 4; r++) {
            int m = wid * 16 + ((lane >> 4) << 2) + r;
            int o = n * 16 + (lane & 15);
            ht[swz(m, o, 128)] = (short)f2bf(fmaxf(accH[n][r], 0.f));
        }
    __syncthreads();
    // conv2 (K=128) + bias
    f32x4 acc2[4];
    #pragma unroll
    for (int n = 0; n < 4; n++) {
        float bv = b2[n * 16 + (lane & 15)];
        f32x4 v = {bv, bv, bv, bv};
        acc2[n] = v;
    }
    #pragma unroll
    for (int ks = 0; ks < 4; ks++) {
        int k0 = ks * 32 + (lane >> 4) * 8;
        short8 a = *(short8*)&ht[swz(mpix, k0, 128)];
        #pragma unroll
        for (int n = 0; n < 4; n++) {
            short8 bb = *(short8*)&w2s[swz(n * 16 + (lane & 15), k0, 128)];
            MFMA16(acc2[n], a, bb);
        }
    }
    // residual + store NHWC (+ transpose to Cf for final NCHW)
    float* fo = fout + (size_t)b * 64 * HW;
    #pragma unroll
    for (int n = 0; n < 4; n++)
        #pragma unroll
        for (int r = 0; r < 4; r++) {
            int m = wid * 16 + ((lane >> 4) << 2) + r;
            int py = m >> 3, px = m & 7;
            int d = n * 16 + (lane & 15);
            size_t addr = (((size_t)(y0 + py)) * 64 + x0 + px) * 64 + d;
            float val = acc2[n][r] + fb[addr];
            fo[addr] = val;
            if (final_step) Cf[d * 68 + m] = val;
        }
    if (final_step) {
        __syncthreads();
        #pragma unroll
        for (int j = 0; j < 4; j++) {
            int i = t + 256 * j;
            int d = i >> 4, pq = (i & 15) << 2;
            int py = pq >> 3, px = pq & 7;
            *(float4*)&fnchw[(((size_t)b * 64 + d) * 64 + y0 + py) * 64 + x0 + px] =
                *(float4*)&Cf[d * 68 + pq];
        }
    }
}

// ---------------- K5: gather -> sampz[z][b][l][c] ----------------
// samp[b,l,c] = sum_{h,w} gyoT[b][h][l]*gxo[b][l][w]*fnchw[b][c][h][w]
__global__ __launch_bounds__(256) void k_gather(const float* __restrict__ fnchw,
        const float* __restrict__ gyoT, const float* __restrict__ gxo,
        float* __restrict__ sampz) {
    __shared__ __align__(16) short At[4096], Bt[4096];
    int t = threadIdx.x, lane = t & 63, wid = t >> 6;
    int lt = blockIdx.x, b = blockIdx.y, zz = blockIdx.z;
    int l0 = lt * 64;
    f32x4 z4 = {0.f, 0.f, 0.f, 0.f};
    f32x4 acc[4] = {z4, z4, z4, z4};
    float4 ga[4], fbq[4];
    float gys[4];
    #pragma unroll
    for (int j = 0; j < 4; j++) {          // gxo rows: chunk-invariant
        int idx = t + 256 * j;
        int row = idx >> 4, wq = (idx & 15) << 2;
        ga[j] = *(const float4*)&gxo[((size_t)b * LL + l0 + row) * 64 + wq];
    }
    {
        int h = zz * 32;
        #pragma unroll
        for (int j = 0; j < 4; j++) {
            int idx = t + 256 * j;
            int row = idx >> 4, wq = (idx & 15) << 2;
            gys[j] = gyoT[((size_t)b * 64 + h) * LL + l0 + row];
            fbq[j] = *(const float4*)&fnchw[(((size_t)b * 64 + row) * 64 + h) * 64 + wq];
        }
    }
    for (int c = 0; c < 32; c++) {
        __syncthreads();
        #pragma unroll
        for (int j = 0; j < 4; j++) {
            int idx = t + 256 * j;
            int row = idx >> 4, wq = (idx & 15) << 2;
            float4 a = {ga[j].x * gys[j], ga[j].y * gys[j],
                        ga[j].z * gys[j], ga[j].w * gys[j]};
            *(short4v*)&At[swz(row, wq, 64)] = cvt4(a);
            *(short4v*)&Bt[swz(row, wq, 64)] = cvt4(fbq[j]);
        }
        __syncthreads();
        if (c < 31) {
            int h = zz * 32 + c + 1;
            #pragma unroll
            for (int j = 0; j < 4; j++) {
                int idx = t + 256 * j;
                int row = idx >> 4, wq = (idx & 15) << 2;
                gys[j] = gyoT[((size_t)b * 64 + h) * LL + l0 + row];
                fbq[j] = *(const float4*)&fnchw[(((size_t)b * 64 + row) * 64 + h) * 64 + wq];
            }
        }
        int mrow = wid * 16 + (lane & 15);
        #pragma unroll
        for (int ks = 0; ks < 2; ks++) {
            int k0 = ks * 32 + (lane >> 4) * 8;
            short8 a = *(short8*)&At[swz(mrow, k0, 64)];
            #pragma unroll
            for (int n = 0; n < 4; n++) {
                short8 bb = *(short8*)&Bt[swz(n * 16 + (lane & 15), k0, 64)];
                MFMA16(acc[n], a, bb);
            }
        }
    }
    #pragma unroll
    for (int n = 0; n < 4; n++)
        #pragma unroll
        for (int r = 0; r < 4; r++) {
            int lr = wid * 16 + ((lane >> 4) << 2) + r;
            int cc = n * 16 + (lane & 15);
            sampz[(((size_t)zz * BB + b) * LL + l0 + lr) * 64 + cc] = acc[n][r];
        }
}

// ---------------- K6: out[bl][e] = sum_d (s0+s1)[bl][d] * wff[e][d] ----------------
__global__ __launch_bounds__(256) void k_out(const float* __restrict__ s0,
        const float* __restrict__ s1, const float* __restrict__ wff,
        float* __restrict__ out) {
    __shared__ __align__(16) short At[4096], Bt[4096];
    int t = threadIdx.x, lane = t & 63, wid = t >> 6;
    int mt = blockIdx.x, e0 = blockIdx.y * 64;
    #pragma unroll
    for (int j = 0; j < 4; j++) {
        int idx = t + 256 * j;
        int row = idx >> 4, kq = (idx & 15) << 2;
        float4 v0 = *(const float4*)&s0[((size_t)mt * 64 + row) * 64 + kq];
        float4 v1 = *(const float4*)&s1[((size_t)mt * 64 + row) * 64 + kq];
        float4 vs = {v0.x + v1.x, v0.y + v1.y, v0.z + v1.z, v0.w + v1.w};
        *(short4v*)&At[swz(row, kq, 64)] = cvt4(vs);
        float4 wv = *(const float4*)&wff[(size_t)(e0 + row) * 64 + kq];
        *(short4v*)&Bt[swz(row, kq, 64)] = cvt4(wv);
    }
    __syncthreads();
    f32x4 z = {0.f, 0.f, 0.f, 0.f};
    f32x4 acc[4] = {z, z, z, z};
    int mrow = wid * 16 + (lane & 15);
    #pragma unroll
    for (int ks = 0; ks < 2; ks++) {
        int k0 = ks * 32 + (lane >> 4) * 8;
        short8 a = *(short8*)&At[swz(mrow, k0, 64)];
        #pragma unroll
        for (int n = 0; n < 4; n++) {
            short8 bb = *(short8*)&Bt[swz(n * 16 + (lane & 15), k0, 64)];
            MFMA16(acc[n], a, bb);
        }
    }
    #pragma unroll
    for (int n = 0; n < 4; n++)
        #pragma unroll
        for (int r = 0; r < 4; r++) {
            int lr = wid * 16 + ((lane >> 4) << 2) + r;
            int ec = e0 + n * 16 + (lane & 15);
            out[((size_t)mt * 64 + lr) * EE + ec] = acc[n][r];
        }
}

extern "C" void kernel_launch(void* const* d_in, const int* in_sizes, int n_in,
                              void* d_out, int out_size, void* d_ws, size_t ws_size,
                              hipStream_t stream) {
    const float* tokens = (const float*)d_in[0];
    const float* pos    = (const float*)d_in[1];
    const float* wtf    = (const float*)d_in[2];
    const float* wff    = (const float*)d_in[3];
    const float* w1     = (const float*)d_in[4];
    const float* b1     = (const float*)d_in[5];
    const float* w2     = (const float*)d_in[6];
    const float* b2     = (const float*)d_in[7];
    const float* lsig   = (const float*)d_in[8];
    float* out = (float*)d_out;

    const size_t M1 = 1048576;
    float* ws    = (float*)d_ws;
    float* gyiT  = ws;              // 1M   [dead after scatter]
    float* gxiT  = ws + 1 * M1;     // 1M   [dead after scatter]
    float* projT = ws + 2 * M1;     // 1M   [dead after scatter]
    float* gyoT  = ws + 3 * M1;     // 1M  (live through gather)
    float* gxo   = ws + 4 * M1;     // 1M  (live through gather)
    float* fA    = ws + 5 * M1;     // 2M  (NHWC)
    float* fB    = ws + 7 * M1;     // 2M  (NHWC)
    short* w1b   = (short*)(ws + 9 * M1);   // 73728 bf16
    short* w2b   = w1b + 73728;             // 8192 bf16
    // aliases (regions dead by the time they're written):
    float* fnchw = ws;              // 2M over gyiT+gxiT (dead after scatter)
    float* samp0 = ws + 7 * M1;     // 2M over fB (dead after final conv):
    float* samp1 = ws + 8 * M1;     //   gather z=0 -> [7M,8M), z=1 -> [8M,9M)

    hipLaunchKernelGGL(k_reorder, dim3(288), dim3(256), 0, stream, w1, w2, w1b, w2b);
    hipLaunchKernelGGL(k_gauss, dim3(32, 8), dim3(256), 0, stream,
                       pos, lsig, gyiT, gxiT, gyoT, gxo);
    hipLaunchKernelGGL(k_proj, dim3(256), dim3(256), 0, stream, tokens, wtf, projT);
    hipLaunchKernelGGL(k_scatter, dim3(32, 8), dim3(256), 0, stream,
                       projT, gyiT, gxiT, fA);
    const float* ci = fA;
    float* co = fB;
    for (int s = 0; s < 5; s++) {
        hipLaunchKernelGGL(k_conv, dim3(64, 8), dim3(256), 0, stream,
                           ci, co, w1b, b1, w2b, b2, fnchw, (s == 4) ? 1 : 0);
        float* tmp = co; co = (float*)ci; ci = tmp;
    }
    hipLaunchKernelGGL(k_gather, dim3(32, 8, 2), dim3(256), 0, stream,
                       fnchw, gyoT, gxo, samp0);
    hipLaunchKernelGGL(k_out, dim3(256, 8), dim3(256), 0, stream,
                       samp0, samp1, wff, out);
}

// Round 4
// 244.134 us; speedup vs baseline: 4.5435x; 1.0664x over previous
//
#include <hip/hip_runtime.h>
#include <cmath>
#include <cstddef>

#define BB 8
#define LL 2048
#define EE 512
#define HW 4096

typedef __attribute__((ext_vector_type(8))) short short8;
typedef __attribute__((ext_vector_type(4))) short short4v;
typedef __attribute__((ext_vector_type(4))) float f32x4;

// XOR-swizzled LDS index (bf16 elements). ldk = row length in bf16 elems.
__device__ __forceinline__ int swz(int row, int k, int ldk) {
    int g = (k >> 3) ^ (row & ((ldk >> 3) - 1));
    return row * ldk + (g << 3) + (k & 7);
}
__device__ __forceinline__ unsigned short f2bf(float f) {   // RNE f32->bf16
    unsigned u = __builtin_bit_cast(unsigned, f);
    return (unsigned short)((u + 0x7FFFu + ((u >> 16) & 1u)) >> 16);
}
__device__ __forceinline__ float bf2f(short s) {
    return __builtin_bit_cast(float, (unsigned)((unsigned short)s) << 16);
}
__device__ __forceinline__ short4v cvt4(float4 v) {
    short4v r;
    r[0] = (short)f2bf(v.x); r[1] = (short)f2bf(v.y);
    r[2] = (short)f2bf(v.z); r[3] = (short)f2bf(v.w);
    return r;
}
#define MFMA16(acc, a, b) acc = __builtin_amdgcn_mfma_f32_16x16x32_bf16(a, b, acc, 0, 0, 0)

// ---------------- K0: weight reorders -> bf16 ----------------
// w1b[(tap*128+o)*64+c] = w1[o,c,ky,kx]  (tap=ky*3+kx);  w2b[d*128+o] = w2[d,o]
__global__ __launch_bounds__(256) void k_reorder(const float* __restrict__ w1,
        const float* __restrict__ w2,
        short* __restrict__ w1b, short* __restrict__ w2b) {
    int i = blockIdx.x * 256 + threadIdx.x;
    if (i < 73728) {
        int c = i & 63, o = (i >> 6) & 127, tap = i >> 13;
        w1b[i] = (short)f2bf(w1[(size_t)o * 576 + c * 9 + tap]);
    }
    if (i < 8192) w2b[i] = (short)f2bf(w2[i]);
}

// ---------------- K1: separable gaussians -> bf16 tables ----------------
// gyiT[b][h][l] (with /Zi), gxiT[b][w][l], gyoT[b][h][l] (with /Zo), gxo[b][l][w]
__global__ __launch_bounds__(256) void k_gauss(const float* __restrict__ pos,
        const float* __restrict__ lsig,
        short* __restrict__ gyiT, short* __restrict__ gxiT,
        short* __restrict__ gyoT, short* __restrict__ gxo) {
    __shared__ float red[4][4][64];
    __shared__ float tile[64 * 65];
    int t = threadIdx.x;
    int ll = t & 63, q = t >> 6;
    int b = blockIdx.y, lt = blockIdx.x;
    int bl = b * LL + lt * 64 + ll;
    float py = pos[(size_t)bl * 2 + 0];
    float px = pos[(size_t)bl * 2 + 1];
    float ls = lsig[0];
    float si = log1pf(expf(ls)) + 1e-6f;
    float so = si * 2.0f;
    float ai = 0.5f / (si * si), ao = 0.5f / (so * so);
    float vyi[16], vxi[16], vyo[16], vxo[16];
    float pyi = 0.f, pxi = 0.f, pyo = 0.f, pxo = 0.f;
    #pragma unroll
    for (int j = 0; j < 16; j++) {
        float g = (float)(q * 16 + j);
        float dy = g - py, dx = g - px;
        float dy2 = dy * dy, dx2 = dx * dx;
        vyi[j] = expf(-dy2 * ai); pyi += vyi[j];
        vxi[j] = expf(-dx2 * ai); pxi += vxi[j];
        vyo[j] = expf(-dy2 * ao); pyo += vyo[j];
        vxo[j] = expf(-dx2 * ao); pxo += vxo[j];
    }
    red[0][q][ll] = pyi; red[1][q][ll] = pxi;
    red[2][q][ll] = pyo; red[3][q][ll] = pxo;
    __syncthreads();
    float syi = red[0][0][ll] + red[0][1][ll] + red[0][2][ll] + red[0][3][ll];
    float sxi = red[1][0][ll] + red[1][1][ll] + red[1][2][ll] + red[1][3][ll];
    float syo = red[2][0][ll] + red[2][1][ll] + red[2][2][ll] + red[2][3][ll];
    float sxo = red[3][0][ll] + red[3][1][ll] + red[3][2][ll] + red[3][3][ll];
    float inv_i = 1.0f / (syi * sxi + 1e-6f);
    float inv_o = 1.0f / (syo * sxo + 1e-6f);
    size_t base = (size_t)b * 64 * LL + lt * 64 + ll;   // [b][*][l]
    #pragma unroll
    for (int j = 0; j < 16; j++) {
        size_t off = base + (size_t)(q * 16 + j) * LL;
        gyiT[off] = (short)f2bf(vyi[j] * inv_i);
        gxiT[off] = (short)f2bf(vxi[j]);
        gyoT[off] = (short)f2bf(vyo[j] * inv_o);
        tile[(q * 16 + j) * 65 + ll] = vxo[j];
    }
    __syncthreads();
    #pragma unroll
    for (int j = 0; j < 16; j++) {
        int i = t + 256 * j;
        int lo = i >> 6, wo = i & 63;
        gxo[((size_t)b * LL + lt * 64 + lo) * 64 + wo] = (short)f2bf(tile[wo * 65 + lo]);
    }
}

// ---------------- K2: projT[b][d][l] = sum_e wtf[d,e]*tokens[b,l,e]  (bf16 out) ---
__global__ __launch_bounds__(256) void k_proj(const float* __restrict__ tokens,
        const float* __restrict__ wtf, short* __restrict__ projT) {
    __shared__ __align__(16) short At[4096], Bt[4096];
    int t = threadIdx.x, lane = t & 63, wid = t >> 6;
    int blk = blockIdx.x;
    int b = blk >> 5;
    int l0b = (blk & 31) * 64;
    size_t tokbase = ((size_t)b * LL + l0b) * EE;
    f32x4 z = {0.f, 0.f, 0.f, 0.f};
    f32x4 acc[4] = {z, z, z, z};
    float4 pa[4], pb[4];
    #pragma unroll
    for (int j = 0; j < 4; j++) {
        int idx = t + 256 * j;
        int row = idx >> 4, kq = (idx & 15) << 2;
        pa[j] = *(const float4*)&wtf[(size_t)row * EE + kq];
        pb[j] = *(const float4*)&tokens[tokbase + (size_t)row * EE + kq];
    }
    for (int c = 0; c < 8; c++) {
        __syncthreads();
        #pragma unroll
        for (int j = 0; j < 4; j++) {
            int idx = t + 256 * j;
            int row = idx >> 4, kq = (idx & 15) << 2;
            *(short4v*)&At[swz(row, kq, 64)] = cvt4(pa[j]);
            *(short4v*)&Bt[swz(row, kq, 64)] = cvt4(pb[j]);
        }
        __syncthreads();
        if (c < 7) {
            int e0 = (c + 1) * 64;
            #pragma unroll
            for (int j = 0; j < 4; j++) {
                int idx = t + 256 * j;
                int row = idx >> 4, kq = (idx & 15) << 2;
                pa[j] = *(const float4*)&wtf[(size_t)row * EE + e0 + kq];
                pb[j] = *(const float4*)&tokens[tokbase + (size_t)row * EE + e0 + kq];
            }
        }
        int mrow = wid * 16 + (lane & 15);
        #pragma unroll
        for (int ks = 0; ks < 2; ks++) {
            int k0 = ks * 32 + (lane >> 4) * 8;
            short8 a = *(short8*)&At[swz(mrow, k0, 64)];
            #pragma unroll
            for (int n = 0; n < 4; n++) {
                short8 bb = *(short8*)&Bt[swz(n * 16 + (lane & 15), k0, 64)];
                MFMA16(acc[n], a, bb);
            }
        }
    }
    #pragma unroll
    for (int n = 0; n < 4; n++)
        #pragma unroll
        for (int r = 0; r < 4; r++) {
            int d = wid * 16 + ((lane >> 4) << 2) + r;
            int l = l0b + n * 16 + (lane & 15);
            projT[((size_t)b * 64 + d) * LL + l] = (short)f2bf(acc[n][r]);
        }
}

// ---------------- K3: scatter (K-split over l) -> fz[kz] NHWC partials ----------
// fz[kz][b][h][w][c] = sum_{l in kz chunk} proj[c,l]*gy[h,l]*gx[w,l]
__global__ __launch_bounds__(256) void k_scatter(const short* __restrict__ projT,
        const short* __restrict__ gyiT, const short* __restrict__ gxiT,
        float* __restrict__ fz) {
    __shared__ __align__(16) char smem[24576];
    short* At = (short*)smem;               // proj [64c][64l] swz
    short* B0 = At + 4096;                  // gx*gy0 [64w][64l]
    short* B1 = B0 + 4096;                  // gx*gy1
    float* Cf = (float*)smem;               // epilogue overlay
    int t = threadIdx.x, lane = t & 63, wid = t >> 6;
    int hp = blockIdx.x, b = blockIdx.y, kz = blockIdx.z;
    int h0 = hp * 2;
    const short* pj  = projT + (size_t)b * 64 * LL + kz * 512;
    const short* gx  = gxiT + (size_t)b * 64 * LL + kz * 512;
    const short* gy0 = gyiT + ((size_t)b * 64 + h0) * LL + kz * 512;
    const short* gy1 = gy0 + LL;
    f32x4 z = {0.f, 0.f, 0.f, 0.f};
    f32x4 acc0[4] = {z, z, z, z}, acc1[4] = {z, z, z, z};
    short8 pA[2], pX[2], pY0[2], pY1[2];
    #pragma unroll
    for (int j = 0; j < 2; j++) {
        int i = t + 256 * j; int row = i >> 3, g = i & 7;
        pA[j]  = *(const short8*)&pj[(size_t)row * LL + g * 8];
        pX[j]  = *(const short8*)&gx[(size_t)row * LL + g * 8];
        pY0[j] = *(const short8*)&gy0[g * 8];
        pY1[j] = *(const short8*)&gy1[g * 8];
    }
    for (int c = 0; c < 8; c++) {
        __syncthreads();
        #pragma unroll
        for (int j = 0; j < 2; j++) {
            int i = t + 256 * j; int row = i >> 3, g = i & 7;
            short8 b0v, b1v;
            #pragma unroll
            for (int e = 0; e < 8; e++) {
                float gxv = bf2f(pX[j][e]);
                b0v[e] = (short)f2bf(gxv * bf2f(pY0[j][e]));
                b1v[e] = (short)f2bf(gxv * bf2f(pY1[j][e]));
            }
            *(short8*)&At[swz(row, g * 8, 64)] = pA[j];
            *(short8*)&B0[swz(row, g * 8, 64)] = b0v;
            *(short8*)&B1[swz(row, g * 8, 64)] = b1v;
        }
        __syncthreads();
        if (c < 7) {
            int l0 = (c + 1) * 64;
            #pragma unroll
            for (int j = 0; j < 2; j++) {
                int i = t + 256 * j; int row = i >> 3, g = i & 7;
                pA[j]  = *(const short8*)&pj[(size_t)row * LL + l0 + g * 8];
                pX[j]  = *(const short8*)&gx[(size_t)row * LL + l0 + g * 8];
                pY0[j] = *(const short8*)&gy0[l0 + g * 8];
                pY1[j] = *(const short8*)&gy1[l0 + g * 8];
            }
        }
        int mrow = wid * 16 + (lane & 15);
        #pragma unroll
        for (int ks = 0; ks < 2; ks++) {
            int k0 = ks * 32 + (lane >> 4) * 8;
            short8 a = *(short8*)&At[swz(mrow, k0, 64)];
            #pragma unroll
            for (int n = 0; n < 4; n++) {
                short8 b0f = *(short8*)&B0[swz(n * 16 + (lane & 15), k0, 64)];
                short8 b1f = *(short8*)&B1[swz(n * 16 + (lane & 15), k0, 64)];
                MFMA16(acc0[n], a, b0f);
                MFMA16(acc1[n], a, b1f);
            }
        }
    }
    float* dst = fz + (size_t)kz * 2097152;
    #pragma unroll
    for (int p = 0; p < 2; p++) {
        __syncthreads();
        #pragma unroll
        for (int n = 0; n < 4; n++)
            #pragma unroll
            for (int r = 0; r < 4; r++) {
                int w = n * 16 + (lane & 15);
                int cc = wid * 16 + ((lane >> 4) << 2) + r;
                Cf[w * 68 + cc] = (p == 0) ? acc0[n][r] : acc1[n][r];
            }
        __syncthreads();
        #pragma unroll
        for (int j = 0; j < 4; j++) {
            int i = t + 256 * j;
            int wo = i >> 4, cq = (i & 15) << 2;
            *(float4*)&dst[(((size_t)b * 64 + h0 + p) * 64 + wo) * 64 + cq] =
                *(float4*)&Cf[wo * 68 + cq];
        }
    }
}

// ---------------- K3b: reduce 4 field partials -> fA (NHWC f32) ----------------
__global__ __launch_bounds__(256) void k_redfield(const float* __restrict__ fz,
        float* __restrict__ fA) {
    const size_t FP = 2097152;
    size_t i = ((size_t)blockIdx.x * 256 + threadIdx.x) * 4;
    float4 a = *(const float4*)&fz[i];
    float4 b = *(const float4*)&fz[i + FP];
    float4 c = *(const float4*)&fz[i + 2 * FP];
    float4 d = *(const float4*)&fz[i + 3 * FP];
    float4 r = {a.x + b.x + c.x + d.x, a.y + b.y + c.y + d.y,
                a.z + b.z + c.z + d.z, a.w + b.w + c.w + d.w};
    *(float4*)&fA[i] = r;
}

// ---------------- K4: fused conv step (implicit GEMM, NHWC, dbuf w1) ------------
__global__ __launch_bounds__(256) void k_conv(const float* __restrict__ fin,
        float* __restrict__ fout,
        const short* __restrict__ w1b, const float* __restrict__ b1,
        const short* __restrict__ w2b, const float* __restrict__ b2,
        short* __restrict__ fnchw, int final_step) {
    __shared__ __align__(16) char smem[78336];
    short* halo = (short*)smem;             // [100 px][64 c] swz64  (12800 B)
    short* w1t  = (short*)(smem + 12800);   // 2 x [128 o][64 c] swz64 (32768 B)
    short* ht   = (short*)(smem + 45568);   // [64 px][128 o] swz128 (16384 B)
    short* w2s  = (short*)(smem + 61952);   // [64 d][128 o] swz128  (16384 B)
    float* Cf   = (float*)smem;             // 17408 B overlay (final epilogue)
    int t = threadIdx.x, lane = t & 63, wid = t >> 6;
    int tile = blockIdx.x, b = blockIdx.y;
    int y0 = (tile >> 3) << 3, x0 = (tile & 7) << 3;
    const float* fb = fin + (size_t)b * 64 * HW;   // NHWC base

    // stage halo (f32 -> bf16, zero-padded)
    for (int i = t; i < 1600; i += 256) {
        int pix = i >> 4, cq = (i & 15) << 2;
        int pr = pix / 10, pc = pix - pr * 10;
        int gy = y0 + pr - 1, gx = x0 + pc - 1;
        float4 v = {0.f, 0.f, 0.f, 0.f};
        if ((unsigned)gy < 64u && (unsigned)gx < 64u)
            v = *(const float4*)&fb[((size_t)gy * 64 + gx) * 64 + cq];
        *(short4v*)&halo[swz(pix, cq, 64)] = cvt4(v);
    }
    // stage w2 (bf16 -> LDS swz128)
    for (int i = t; i < 1024; i += 256) {
        int d = i >> 4, g = i & 15;
        short8 v = *(const short8*)&w2b[(size_t)d * 128 + g * 8];
        *(short8*)&w2s[swz(d, g * 8, 128)] = v;
    }
    // stage w1 tap0 -> buf0
    #pragma unroll
    for (int j = 0; j < 4; j++) {
        int i = t + 256 * j; int o = i >> 3, g = i & 7;
        *(short8*)&w1t[swz(o, g * 8, 64)] = *(const short8*)&w1b[(size_t)o * 64 + g * 8];
    }
    f32x4 accH[8];
    #pragma unroll
    for (int n = 0; n < 8; n++) {
        float bv = b1[n * 16 + (lane & 15)];
        f32x4 v = {bv, bv, bv, bv};
        accH[n] = v;
    }
    __syncthreads();
    // prefetch w1 tap1
    short8 w1pf[4];
    #pragma unroll
    for (int j = 0; j < 4; j++) {
        int i = t + 256 * j; int o = i >> 3, g = i & 7;
        w1pf[j] = *(const short8*)&w1b[((size_t)128 + o) * 64 + g * 8];
    }
    int mpix = wid * 16 + (lane & 15);
    int ppy = mpix >> 3, ppx = mpix & 7;

    #pragma unroll
    for (int tap = 0; tap < 9; tap++) {
        short* buf = w1t + (tap & 1) * 8192;
        if (tap < 8) {
            short* nbuf = w1t + ((tap + 1) & 1) * 8192;
            #pragma unroll
            for (int j = 0; j < 4; j++) {
                int i = t + 256 * j; int o = i >> 3, g = i & 7;
                *(short8*)&nbuf[swz(o, g * 8, 64)] = w1pf[j];
            }
            if (tap < 7) {
                #pragma unroll
                for (int j = 0; j < 4; j++) {
                    int i = t + 256 * j; int o = i >> 3, g = i & 7;
                    w1pf[j] = *(const short8*)&w1b[((size_t)(tap + 2) * 128 + o) * 64 + g * 8];
                }
            }
        }
        int ky = tap / 3, kx = tap - ky * 3;
        int hpix = (ppy + ky) * 10 + (ppx + kx);
        #pragma unroll
        for (int ks = 0; ks < 2; ks++) {
            int k0 = ks * 32 + (lane >> 4) * 8;
            short8 a = *(short8*)&halo[swz(hpix, k0, 64)];
            #pragma unroll
            for (int n = 0; n < 8; n++) {
                short8 bb = *(short8*)&buf[swz(n * 16 + (lane & 15), k0, 64)];
                MFMA16(accH[n], a, bb);
            }
        }
        __syncthreads();
    }
    // relu -> ht (bf16)
    #pragma unroll
    for (int n = 0; n < 8; n++)
        #pragma unroll
        for (int r = 0; r < 4; r++) {
            int m = wid * 16 + ((lane >> 4) << 2) + r;
            int o = n * 16 + (lane & 15);
            ht[swz(m, o, 128)] = (short)f2bf(fmaxf(accH[n][r], 0.f));
        }
    __syncthreads();
    // conv2 (K=128) + bias
    f32x4 acc2[4];
    #pragma unroll
    for (int n = 0; n < 4; n++) {
        float bv = b2[n * 16 + (lane & 15)];
        f32x4 v = {bv, bv, bv, bv};
        acc2[n] = v;
    }
    #pragma unroll
    for (int ks = 0; ks < 4; ks++) {
        int k0 = ks * 32 + (lane >> 4) * 8;
        short8 a = *(short8*)&ht[swz(mpix, k0, 128)];
        #pragma unroll
        for (int n = 0; n < 4; n++) {
            short8 bb = *(short8*)&w2s[swz(n * 16 + (lane & 15), k0, 128)];
            MFMA16(acc2[n], a, bb);
        }
    }
    // residual + store
    float* fo = fout + (size_t)b * 64 * HW;
    #pragma unroll
    for (int n = 0; n < 4; n++)
        #pragma unroll
        for (int r = 0; r < 4; r++) {
            int m = wid * 16 + ((lane >> 4) << 2) + r;
            int py = m >> 3, px = m & 7;
            int d = n * 16 + (lane & 15);
            size_t addr = (((size_t)(y0 + py)) * 64 + x0 + px) * 64 + d;
            float val = acc2[n][r] + fb[addr];
            if (!final_step) fo[addr] = val;
            else Cf[d * 68 + m] = val;
        }
    if (final_step) {   // transpose to bf16 NCHW for gather
        __syncthreads();
        #pragma unroll
        for (int j = 0; j < 4; j++) {
            int i = t + 256 * j;
            int d = i >> 4, pq = (i & 15) << 2;
            int py = pq >> 3, px = pq & 7;
            float4 v = *(float4*)&Cf[d * 68 + pq];
            *(short4v*)&fnchw[(((size_t)b * 64 + d) * 64 + y0 + py) * 64 + x0 + px] =
                cvt4(v);
        }
    }
}

// ---------------- K5: gather (z-split over h) -> sampz[z][b][l][c] ----------------
__global__ __launch_bounds__(256) void k_gather(const short* __restrict__ fnchw,
        const short* __restrict__ gyoT, const short* __restrict__ gxo,
        float* __restrict__ sampz) {
    __shared__ __align__(16) short At[4096], Bt[4096];
    int t = threadIdx.x, lane = t & 63, wid = t >> 6;
    int lt = blockIdx.x, b = blockIdx.y, zz = blockIdx.z;
    int l0 = lt * 64;
    f32x4 z4 = {0.f, 0.f, 0.f, 0.f};
    f32x4 acc[4] = {z4, z4, z4, z4};
    short8 pX[2], pF[2];
    float gyv[2];
    #pragma unroll
    for (int j = 0; j < 2; j++) {      // gxo rows: chunk-invariant
        int i = t + 256 * j; int row = i >> 3, g = i & 7;
        pX[j] = *(const short8*)&gxo[((size_t)b * LL + l0 + row) * 64 + g * 8];
    }
    int h0 = zz * 16;
    #pragma unroll
    for (int j = 0; j < 2; j++) {
        int i = t + 256 * j; int row = i >> 3, g = i & 7;
        gyv[j] = bf2f(gyoT[((size_t)b * 64 + h0) * LL + l0 + row]);
        pF[j] = *(const short8*)&fnchw[(((size_t)b * 64 + row) * 64 + h0) * 64 + g * 8];
    }
    for (int c = 0; c < 16; c++) {
        __syncthreads();
        #pragma unroll
        for (int j = 0; j < 2; j++) {
            int i = t + 256 * j; int row = i >> 3, g = i & 7;
            short8 a;
            #pragma unroll
            for (int e = 0; e < 8; e++)
                a[e] = (short)f2bf(bf2f(pX[j][e]) * gyv[j]);
            *(short8*)&At[swz(row, g * 8, 64)] = a;
            *(short8*)&Bt[swz(row, g * 8, 64)] = pF[j];
        }
        __syncthreads();
        if (c < 15) {
            int h = h0 + c + 1;
            #pragma unroll
            for (int j = 0; j < 2; j++) {
                int i = t + 256 * j; int row = i >> 3, g = i & 7;
                gyv[j] = bf2f(gyoT[((size_t)b * 64 + h) * LL + l0 + row]);
                pF[j] = *(const short8*)&fnchw[(((size_t)b * 64 + row) * 64 + h) * 64 + g * 8];
            }
        }
        int mrow = wid * 16 + (lane & 15);
        #pragma unroll
        for (int ks = 0; ks < 2; ks++) {
            int k0 = ks * 32 + (lane >> 4) * 8;
            short8 a = *(short8*)&At[swz(mrow, k0, 64)];
            #pragma unroll
            for (int n = 0; n < 4; n++) {
                short8 bb = *(short8*)&Bt[swz(n * 16 + (lane & 15), k0, 64)];
                MFMA16(acc[n], a, bb);
            }
        }
    }
    #pragma unroll
    for (int n = 0; n < 4; n++)
        #pragma unroll
        for (int r = 0; r < 4; r++) {
            int lr = wid * 16 + ((lane >> 4) << 2) + r;
            int cc = n * 16 + (lane & 15);
            sampz[(((size_t)zz * BB + b) * LL + l0 + lr) * 64 + cc] = acc[n][r];
        }
}

// ---------------- K6: out[bl][e] = sum_d (sum_z samp[z])[bl][d] * wff[e][d] -------
__global__ __launch_bounds__(256) void k_out(const float* __restrict__ samp,
        const float* __restrict__ wff, float* __restrict__ out) {
    __shared__ __align__(16) short At[4096], Bt[4096];
    const size_t SP = 1048576;
    int t = threadIdx.x, lane = t & 63, wid = t >> 6;
    int mt = blockIdx.x, e0 = blockIdx.y * 64;
    #pragma unroll
    for (int j = 0; j < 4; j++) {
        int idx = t + 256 * j;
        int row = idx >> 4, kq = (idx & 15) << 2;
        size_t off = ((size_t)mt * 64 + row) * 64 + kq;
        float4 v0 = *(const float4*)&samp[off];
        float4 v1 = *(const float4*)&samp[off + SP];
        float4 v2 = *(const float4*)&samp[off + 2 * SP];
        float4 v3 = *(const float4*)&samp[off + 3 * SP];
        float4 vs = {v0.x + v1.x + v2.x + v3.x, v0.y + v1.y + v2.y + v3.y,
                     v0.z + v1.z + v2.z + v3.z, v0.w + v1.w + v2.w + v3.w};
        *(short4v*)&At[swz(row, kq, 64)] = cvt4(vs);
        float4 wv = *(const float4*)&wff[(size_t)(e0 + row) * 64 + kq];
        *(short4v*)&Bt[swz(row, kq, 64)] = cvt4(wv);
    }
    __syncthreads();
    f32x4 z = {0.f, 0.f, 0.f, 0.f};
    f32x4 acc[4] = {z, z, z, z};
    int mrow = wid * 16 + (lane & 15);
    #pragma unroll
    for (int ks = 0; ks < 2; ks++) {
        int k0 = ks * 32 + (lane >> 4) * 8;
        short8 a = *(short8*)&At[swz(mrow, k0, 64)];
        #pragma unroll
        for (int n = 0; n < 4; n++) {
            short8 bb = *(short8*)&Bt[swz(n * 16 + (lane & 15), k0, 64)];
            MFMA16(acc[n], a, bb);
        }
    }
    #pragma unroll
    for (int n = 0; n < 4; n++)
        #pragma unroll
        for (int r = 0; r < 4; r++) {
            int lr = wid * 16 + ((lane >> 4) << 2) + r;
            int ec = e0 + n * 16 + (lane & 15);
            out[((size_t)mt * 64 + lr) * EE + ec] = acc[n][r];
        }
}

extern "C" void kernel_launch(void* const* d_in, const int* in_sizes, int n_in,
                              void* d_out, int out_size, void* d_ws, size_t ws_size,
                              hipStream_t stream) {
    const float* tokens = (const float*)d_in[0];
    const float* pos    = (const float*)d_in[1];
    const float* wtf    = (const float*)d_in[2];
    const float* wff    = (const float*)d_in[3];
    const float* w1     = (const float*)d_in[4];
    const float* b1     = (const float*)d_in[5];
    const float* w2     = (const float*)d_in[6];
    const float* b2     = (const float*)d_in[7];
    const float* lsig   = (const float*)d_in[8];
    float* out = (float*)d_out;

    const size_t M1 = 1048576;          // 1M (floats or shorts as noted)
    float* ws    = (float*)d_ws;
    short* sbase = (short*)d_ws;
    short* gyiT  = sbase;               // 1M shorts
    short* gxiT  = sbase + 1 * M1;
    short* gyoT  = sbase + 2 * M1;
    short* gxo   = sbase + 3 * M1;
    short* projT = sbase + 4 * M1;      // ends at 2.5M floats
    float* fz    = ws + 3 * M1;         // 4 x 2M floats (partial fields)
    float* fA    = ws + 11 * M1;        // 2M floats NHWC
    float* fB    = ws + 13 * M1;        // 2M floats NHWC
    short* fnchw = (short*)(ws + 15 * M1);  // 2M shorts (bf16 NCHW)
    float* samp  = ws + 16 * M1;        // 4 x 1M floats (gather partials)
    short* w1b   = (short*)(ws + 20 * M1);  // 73728 bf16
    short* w2b   = w1b + 73728;             // 8192 bf16

    hipLaunchKernelGGL(k_reorder, dim3(288), dim3(256), 0, stream, w1, w2, w1b, w2b);
    hipLaunchKernelGGL(k_gauss, dim3(32, 8), dim3(256), 0, stream,
                       pos, lsig, gyiT, gxiT, gyoT, gxo);
    hipLaunchKernelGGL(k_proj, dim3(256), dim3(256), 0, stream, tokens, wtf, projT);
    hipLaunchKernelGGL(k_scatter, dim3(32, 8, 4), dim3(256), 0, stream,
                       projT, gyiT, gxiT, fz);
    hipLaunchKernelGGL(k_redfield, dim3(2048), dim3(256), 0, stream, fz, fA);
    const float* ci = fA;
    float* co = fB;
    for (int s = 0; s < 5; s++) {
        hipLaunchKernelGGL(k_conv, dim3(64, 8), dim3(256), 0, stream,
                           ci, co, w1b, b1, w2b, b2, fnchw, (s == 4) ? 1 : 0);
        float* tmp = co; co = (float*)ci; ci = tmp;
    }
    hipLaunchKernelGGL(k_gather, dim3(32, 8, 4), dim3(256), 0, stream,
                       fnchw, gyoT, gxo, samp);
    hipLaunchKernelGGL(k_out, dim3(256, 8), dim3(256), 0, stream,
                       samp, wff, out);
}